// Round 1
// baseline (2244.307 us; speedup 1.0000x reference)
//
#include <hip/hip_runtime.h>

// MoE layer: x[8,4096,512] f32, assign[8,4096,2] int, W1[8,512,2048], b1[8,2048],
// W2[8,2048,512], b2[8,512]. out[8,4096,512] f32.
// Strategy: route tokens into per-expert lists (ws), then fused grouped GEMM
// (bf16 MFMA 16x16x32) per (expert, 64-token tile).

#define NTOK  32768
#define DIM   512
#define HID   2048
#define NE    8
#define TILE_M 64
#define HC    64            // hidden chunk
#define NCHUNK (HID / HC)   // 32
#define KC    64            // K chunk for GEMM1

typedef __attribute__((ext_vector_type(8))) short short8;   // 8 bf16 (4 VGPRs)
typedef __attribute__((ext_vector_type(4))) float f32x4;
typedef __attribute__((ext_vector_type(4))) unsigned short us4;

__device__ __forceinline__ unsigned short f2bf(float f) {
  union { float f; unsigned u; } v; v.f = f;
  unsigned r = v.u + 0x7FFFu + ((v.u >> 16) & 1u);   // RNE
  return (unsigned short)(r >> 16);
}

// ---------------- routing ----------------
__global__ void moe_route(const int* __restrict__ assign, int* __restrict__ cnt,
                          int* __restrict__ lists) {
  int t = blockIdx.x * blockDim.x + threadIdx.x;
  if (t >= NTOK) return;
  int a0 = assign[2 * t + 0];
  int a1 = assign[2 * t + 1];
  if (a0 == a1) {
    int p = atomicAdd(&cnt[a0], 1);
    lists[a0 * NTOK + p] = t | 0x10000;          // weight 1.0
  } else {
    int p0 = atomicAdd(&cnt[a0], 1);
    lists[a0 * NTOK + p0] = t;                   // weight 0.5
    int p1 = atomicAdd(&cnt[a1], 1);
    lists[a1 * NTOK + p1] = t;
  }
}

// ---------------- fused expert GEMM ----------------
// LDS layout (bytes):
#define OFF_X   0                         // X tile:  64 x 520 ushort = 66560
#define OFF_W1  66560                     // W1t:     64 x 72 ushort  = 9216
#define OFF_H   (66560 + 9216)            // h:       64 x 72 ushort  = 9216
#define OFF_W2  (66560 + 9216 + 9216)     // W2t:    512 x 72 ushort  = 73728
#define OFF_TOK (OFF_W2 + 73728)          // 64 int  = 256
#define OFF_WGT (OFF_TOK + 256)           // 64 f32  = 256
#define LDS_BYTES (OFF_WGT + 256)         // 159232 <= 163840

__global__ __launch_bounds__(512, 2) void moe_gemm(
    const float* __restrict__ x, const float* __restrict__ W1,
    const float* __restrict__ b1, const float* __restrict__ W2,
    const float* __restrict__ b2, const int* __restrict__ cnt,
    const int* __restrict__ lists, float* __restrict__ out) {
  extern __shared__ char smem[];
  unsigned short* Xs  = (unsigned short*)(smem + OFF_X);
  unsigned short* W1t = (unsigned short*)(smem + OFF_W1);
  unsigned short* Hs  = (unsigned short*)(smem + OFF_H);
  unsigned short* W2t = (unsigned short*)(smem + OFF_W2);
  int*   tok = (int*)(smem + OFF_TOK);
  float* wgt = (float*)(smem + OFF_WGT);

  const int e   = blockIdx.y;
  const int n_e = cnt[e];
  const int t0  = blockIdx.x * TILE_M;
  if (t0 >= n_e) return;

  const int tid  = threadIdx.x;
  const int wid  = tid >> 6;        // 0..7
  const int lane = tid & 63;
  const int lr   = lane & 15;       // A-row / B-col / D-col in frag
  const int lg   = lane >> 4;       // k-group (A/B), row-group (D)

  if (tid < TILE_M) {
    int idx = t0 + tid;
    if (idx < n_e) {
      int p = lists[e * NTOK + idx];
      tok[tid] = p & 0xFFFF;
      wgt[tid] = (p & 0x10000) ? 1.0f : 0.5f;
    } else {
      tok[tid] = -1;
      wgt[tid] = 0.0f;
    }
  }
  __syncthreads();

  // ---- stage X tile (fp32 -> bf16), 64 rows x 512 cols ----
  {
    const int m = tid >> 3;       // row 0..63
    const int g = tid & 7;
    const int trow = tok[m];
    if (trow >= 0) {
      const float4* xr = (const float4*)(x + (size_t)trow * DIM);
#pragma unroll
      for (int i = 0; i < 16; ++i) {
        int c4 = g + 8 * i;       // float4 col 0..127
        float4 v = xr[c4];
        us4 pk;
        pk.x = f2bf(v.x); pk.y = f2bf(v.y); pk.z = f2bf(v.z); pk.w = f2bf(v.w);
        *(us4*)&Xs[m * 520 + c4 * 4] = pk;
      }
    } else {
      us4 zz; zz.x = 0; zz.y = 0; zz.z = 0; zz.w = 0;
#pragma unroll
      for (int i = 0; i < 16; ++i) {
        int c4 = g + 8 * i;
        *(us4*)&Xs[m * 520 + c4 * 4] = zz;
      }
    }
  }
  // X writes are fenced by the first barrier inside the kk loop.

  f32x4 acc2[4][4];
#pragma unroll
  for (int i = 0; i < 4; ++i)
#pragma unroll
    for (int j = 0; j < 4; ++j) acc2[i][j] = f32x4{0.f, 0.f, 0.f, 0.f};

  const int mf1 = wid & 3;           // GEMM1 m-frag (rows 16*mf1..)
  const int nb1 = (wid >> 2) * 32;   // GEMM1 n base (cols nb1..nb1+31)

  for (int c = 0; c < NCHUNK; ++c) {
    // ================= GEMM1: h = relu(X @ W1[:, c*64:+64] + b1) =================
    f32x4 acc1[2];
    acc1[0] = f32x4{0.f, 0.f, 0.f, 0.f};
    acc1[1] = f32x4{0.f, 0.f, 0.f, 0.f};
    for (int kk = 0; kk < 8; ++kk) {
      __syncthreads();   // fences prev readers of W1t (and prev-chunk GEMM2 reads)
      {  // stage W1t piece transposed: [n 0..63][k 0..63]
        int n  = tid & 63;
        int kb = (tid >> 6) * 8;
        const float* src = W1 + ((size_t)e * DIM + kk * KC + kb) * HID + c * HC + n;
        short8 pk;
#pragma unroll
        for (int j = 0; j < 8; ++j) pk[j] = (short)f2bf(src[(size_t)j * HID]);
        *(short8*)&W1t[n * 72 + kb] = pk;
      }
      __syncthreads();
#pragma unroll
      for (int kf = 0; kf < 2; ++kf) {
        short8 a = *(const short8*)&Xs[(mf1 * 16 + lr) * 520 + kk * 64 + kf * 32 + lg * 8];
#pragma unroll
        for (int nf = 0; nf < 2; ++nf) {
          short8 b = *(const short8*)&W1t[(nb1 + nf * 16 + lr) * 72 + kf * 32 + lg * 8];
          acc1[nf] = __builtin_amdgcn_mfma_f32_16x16x32_bf16(a, b, acc1[nf], 0, 0, 0);
        }
      }
    }
    // write h (bias + relu -> bf16). Prev-chunk readers of Hs fenced by kk-loop barriers.
#pragma unroll
    for (int nf = 0; nf < 2; ++nf) {
      int ncol = nb1 + nf * 16 + lr;
      float bias = b1[e * HID + c * HC + ncol];
#pragma unroll
      for (int r = 0; r < 4; ++r) {
        float hv = acc1[nf][r] + bias;
        hv = fmaxf(hv, 0.0f);
        Hs[(mf1 * 16 + lg * 4 + r) * 72 + ncol] = f2bf(hv);
      }
    }
    {  // stage W2t transposed: [n 0..511][k 0..63] of W2[e][c*64:+64][:]
      int n = tid;
      const float* src = W2 + ((size_t)e * HID + c * HC) * DIM + n;
      for (int j8 = 0; j8 < 8; ++j8) {
        short8 pk;
#pragma unroll
        for (int j = 0; j < 8; ++j) pk[j] = (short)f2bf(src[(size_t)(j8 * 8 + j) * DIM]);
        *(short8*)&W2t[n * 72 + j8 * 8] = pk;
      }
    }
    __syncthreads();
    // ================= GEMM2: out_acc += h @ W2chunk =================
#pragma unroll
    for (int kf = 0; kf < 2; ++kf) {
      short8 a[4], b[4];
#pragma unroll
      for (int mf = 0; mf < 4; ++mf)
        a[mf] = *(const short8*)&Hs[(mf * 16 + lr) * 72 + kf * 32 + lg * 8];
#pragma unroll
      for (int nf = 0; nf < 4; ++nf)
        b[nf] = *(const short8*)&W2t[(wid * 64 + nf * 16 + lr) * 72 + kf * 32 + lg * 8];
#pragma unroll
      for (int mf = 0; mf < 4; ++mf)
#pragma unroll
        for (int nf = 0; nf < 4; ++nf)
          acc2[mf][nf] = __builtin_amdgcn_mfma_f32_16x16x32_bf16(a[mf], b[nf], acc2[mf][nf], 0, 0, 0);
    }
    // next chunk's first kk-barrier fences these LDS reads before overwrite
  }

  // ---- epilogue: out[t] += (acc + b2) * w ----
#pragma unroll
  for (int mf = 0; mf < 4; ++mf) {
#pragma unroll
    for (int r = 0; r < 4; ++r) {
      int m = mf * 16 + lg * 4 + r;
      int t = tok[m];
      if (t < 0) continue;
      float wv = wgt[m];
#pragma unroll
      for (int nf = 0; nf < 4; ++nf) {
        int n = wid * 64 + nf * 16 + lr;
        float v = (acc2[mf][nf][r] + b2[e * DIM + n]) * wv;
        atomicAdd(&out[(size_t)t * DIM + n], v);
      }
    }
  }
}

extern "C" void kernel_launch(void* const* d_in, const int* in_sizes, int n_in,
                              void* d_out, int out_size, void* d_ws, size_t ws_size,
                              hipStream_t stream) {
  const float* x      = (const float*)d_in[0];
  const int*   assign = (const int*)d_in[1];
  const float* W1     = (const float*)d_in[2];
  const float* b1     = (const float*)d_in[3];
  const float* W2     = (const float*)d_in[4];
  const float* b2     = (const float*)d_in[5];
  float* out = (float*)d_out;

  int* cnt   = (int*)d_ws;
  int* lists = (int*)((char*)d_ws + 256);   // NE * NTOK ints = 1 MB

  hipMemsetAsync(d_out, 0, (size_t)out_size * sizeof(float), stream);
  hipMemsetAsync(cnt, 0, NE * sizeof(int), stream);

  moe_route<<<NTOK / 256, 256, 0, stream>>>(assign, cnt, lists);

  hipFuncSetAttribute((const void*)moe_gemm,
                      hipFuncAttributeMaxDynamicSharedMemorySize, LDS_BYTES);
  dim3 grid(NTOK / TILE_M, NE);   // 512 tiles max per expert x 8 experts
  moe_gemm<<<grid, 512, LDS_BYTES, stream>>>(x, W1, b1, W2, b2, cnt, lists, out);
}

// Round 2
// 892.016 us; speedup vs baseline: 2.5160x; 2.5160x over previous
//
#include <hip/hip_runtime.h>

// MoE: x[8,4096,512]f32, assign[8,4096,2]i32, W1[8,512,2048], b1[8,2048],
//      W2[8,2048,512], b2[8,512] -> out[8,4096,512]f32
// v2: pre-convert X/W to bf16 (W transposed) in ws; fused grouped GEMM with
// global_load_lds staging, XOR-swizzled LDS, 2-phase pipeline, XCD affinity.

#define NTOK 32768
#define DIM  512
#define HID  2048
#define NE   8
#define TM   128   // tokens per tile
#define HC   256   // hidden chunk
#define KC   64    // k piece

typedef __attribute__((ext_vector_type(8))) short short8;
typedef __attribute__((ext_vector_type(4))) float f32x4;
typedef __attribute__((ext_vector_type(4))) unsigned short us4;
typedef unsigned short ushort_t;

__device__ __forceinline__ unsigned short f2bf(float f) {
  union { float f; unsigned u; } v; v.f = f;
  unsigned r = v.u + 0x7FFFu + ((v.u >> 16) & 1u);  // RNE
  return (unsigned short)(r >> 16);
}

__device__ __forceinline__ void g2l16(const void* g, void* l) {
  __builtin_amdgcn_global_load_lds(
      (const __attribute__((address_space(1))) void*)g,
      (__attribute__((address_space(3))) void*)l, 16, 0, 0);
}

// ---------------- routing ----------------
__global__ void moe_route(const int* __restrict__ assign, int* __restrict__ cnt,
                          int* __restrict__ lists) {
  int t = blockIdx.x * blockDim.x + threadIdx.x;
  if (t >= NTOK) return;
  int a0 = assign[2 * t + 0];
  int a1 = assign[2 * t + 1];
  if (a0 == a1) {
    int p = atomicAdd(&cnt[a0], 1);
    lists[a0 * NTOK + p] = t | 0x10000;  // weight 1.0
  } else {
    int p0 = atomicAdd(&cnt[a0], 1);
    lists[a0 * NTOK + p0] = t;           // weight 0.5
    int p1 = atomicAdd(&cnt[a1], 1);
    lists[a1 * NTOK + p1] = t;
  }
}

// ---------------- converters ----------------
__global__ __launch_bounds__(256) void cvt_x(const float4* __restrict__ x,
                                             us4* __restrict__ xb) {
  int i = blockIdx.x * 256 + threadIdx.x;
  float4 v = x[i];
  us4 p;
  p.x = f2bf(v.x); p.y = f2bf(v.y); p.z = f2bf(v.z); p.w = f2bf(v.w);
  xb[i] = p;
}

// src: [E][R][C] fp32 -> dst: [E][C][R] bf16 (transpose + convert)
__global__ __launch_bounds__(256) void transp_cvt(const float* __restrict__ src,
                                                  ushort_t* __restrict__ dst,
                                                  int R, int C) {
  __shared__ float tile[64][68];
  const int e = blockIdx.z;
  const int rb = blockIdx.y * 64, cb = blockIdx.x * 64;
  const int t = threadIdx.x;
  {
    const int tr = t >> 2, tc = (t & 3) * 16;
    const float* s = src + ((size_t)e * R + rb + tr) * C + cb + tc;
    float4 v0 = ((const float4*)s)[0];
    float4 v1 = ((const float4*)s)[1];
    float4 v2 = ((const float4*)s)[2];
    float4 v3 = ((const float4*)s)[3];
    *(float4*)&tile[tr][tc + 0]  = v0;
    *(float4*)&tile[tr][tc + 4]  = v1;
    *(float4*)&tile[tr][tc + 8]  = v2;
    *(float4*)&tile[tr][tc + 12] = v3;
  }
  __syncthreads();
  {
    const int n = t >> 2, ks = (t & 3) * 16;
    short8 o0, o1;
#pragma unroll
    for (int j = 0; j < 8; ++j) o0[j] = (short)f2bf(tile[ks + j][n]);
#pragma unroll
    for (int j = 0; j < 8; ++j) o1[j] = (short)f2bf(tile[ks + 8 + j][n]);
    ushort_t* d = dst + ((size_t)e * C + cb + n) * R + rb + ks;
    *(short8*)(d) = o0;
    *(short8*)(d + 8) = o1;
  }
}

// ---------------- fused expert GEMM ----------------
// LDS map (bytes): Xp dbuf 2x16K @0, W dbuf 2x32K @32768, H [128][256] 64K @98304
#define XOFF(par) ((par) * 16384)
#define WOFF(par) (32768 + (par) * 32768)
#define HOFF 98304
#define LDS_BYTES 163840

__global__ __launch_bounds__(512, 1) void moe_gemm(
    const ushort_t* __restrict__ Xb, const ushort_t* __restrict__ W1b,
    const float* __restrict__ b1, const ushort_t* __restrict__ W2b,
    const float* __restrict__ b2, const int* __restrict__ cnt,
    const int* __restrict__ lists, float* __restrict__ out) {
  extern __shared__ char smem[];

  const int id = blockIdx.x;
  const int e = id & 7;          // expert == XCD (round-robin dispatch)
  const int tile = id >> 3;
  const int n_e = cnt[e];
  const int t0 = tile * TM;
  if (t0 >= n_e) return;

  const int tid = threadIdx.x;
  const int wid = tid >> 6;
  const int lane = tid & 63;
  const int lr = lane & 15, lg = lane >> 4;
  const int wm = wid >> 2;  // 0..1 row half
  const int wn = wid & 3;   // 0..3 col quarter

  // staging geometry (fixed per thread)
  const int srow = tid >> 3;          // 0..63
  const int sxor = (tid & 7) ^ (srow & 7);
  int tokA = 0, tokB = 0;
  {
    int i0 = t0 + srow;
    int i1 = t0 + 64 + srow;
    if (i0 < n_e) tokA = lists[e * NTOK + i0] & 0xFFFF;
    if (i1 < n_e) tokB = lists[e * NTOK + i1] & 0xFFFF;
  }
  const ushort_t* gX0 = Xb + (size_t)tokA * DIM + sxor * 8;
  const ushort_t* gX1 = Xb + (size_t)tokB * DIM + sxor * 8;
  const ushort_t* gW1 = W1b + ((size_t)(e * HID) + srow) * DIM + sxor * 8;
  const ushort_t* gW2 = W2b + ((size_t)(e * DIM) + srow) * HID + sxor * 8;

  auto stageX = [&](int p, int par) {
    char* d = smem + XOFF(par) + tid * 16;
    g2l16(gX0 + p * KC, d);
    g2l16(gX1 + p * KC, d + 8192);
  };
  auto stageW1 = [&](int c, int p, int par) {
    char* d = smem + WOFF(par) + tid * 16;
    const ushort_t* g = gW1 + (size_t)(c * HC) * DIM + p * KC;
#pragma unroll
    for (int i = 0; i < 4; ++i) g2l16(g + (size_t)(i * 64) * DIM, d + i * 8192);
  };
  auto stageW2 = [&](int c, int h, int q, int par) {
    char* d = smem + WOFF(par) + tid * 16;
    const ushort_t* g = gW2 + (size_t)(h * 256) * HID + c * HC + q * KC;
#pragma unroll
    for (int i = 0; i < 4; ++i) g2l16(g + (size_t)(i * 64) * HID, d + i * 8192);
  };

  f32x4 acc2[4][8];
#pragma unroll
  for (int i = 0; i < 4; ++i)
#pragma unroll
    for (int j = 0; j < 8; ++j) acc2[i][j] = f32x4{0.f, 0.f, 0.f, 0.f};

  // prologue
  stageX(0, 0);
  stageW1(0, 0, 0);
  __syncthreads();

  for (int c = 0; c < 8; ++c) {
    float b1v[4];
#pragma unroll
    for (int nf = 0; nf < 4; ++nf)
      b1v[nf] = b1[e * HID + c * HC + wn * 64 + nf * 16 + lr];

    f32x4 acc1[4][4];
#pragma unroll
    for (int i = 0; i < 4; ++i)
#pragma unroll
      for (int j = 0; j < 4; ++j) acc1[i][j] = f32x4{0.f, 0.f, 0.f, 0.f};

    // ---- GEMM1: H = relu(X @ W1[:, c*256:+256] + b1), K=512 in 8 pieces ----
#pragma unroll
    for (int p = 0; p < 8; ++p) {
      if (p < 7) { stageX(p + 1, (p + 1) & 1); stageW1(c, p + 1, (p + 1) & 1); }
      else       { stageW2(c, 0, 0, 0); }
      const int xb = XOFF(p & 1);
      const int wb = WOFF(p & 1);
#pragma unroll
      for (int kf = 0; kf < 2; ++kf) {
        short8 av[4], bv[4];
#pragma unroll
        for (int mf = 0; mf < 4; ++mf) {
          int m = wm * 64 + mf * 16 + lr;
          av[mf] = *(const short8*)(smem + xb + m * 128 +
                                    (((kf * 4 + lg) ^ (m & 7)) << 4));
        }
#pragma unroll
        for (int nf = 0; nf < 4; ++nf) {
          int n = wn * 64 + nf * 16 + lr;
          bv[nf] = *(const short8*)(smem + wb + n * 128 +
                                    (((kf * 4 + lg) ^ (n & 7)) << 4));
        }
#pragma unroll
        for (int mf = 0; mf < 4; ++mf)
#pragma unroll
          for (int nf = 0; nf < 4; ++nf)
            acc1[mf][nf] = __builtin_amdgcn_mfma_f32_16x16x32_bf16(
                av[mf], bv[nf], acc1[mf][nf], 0, 0, 0);
      }
      if (p == 7) {
        // bias + relu -> H (swizzled bf16)
#pragma unroll
        for (int mf = 0; mf < 4; ++mf)
#pragma unroll
          for (int nf = 0; nf < 4; ++nf)
#pragma unroll
            for (int r = 0; r < 4; ++r) {
              int m = wm * 64 + mf * 16 + lg * 4 + r;
              int col = wn * 64 + nf * 16 + lr;
              float hv = fmaxf(acc1[mf][nf][r] + b1v[nf], 0.0f);
              *(ushort_t*)(smem + HOFF + m * 512 +
                           ((((col >> 3) ^ (m & 7)) << 4)) + (col & 7) * 2) =
                  f2bf(hv);
            }
      }
      __syncthreads();
    }

    // ---- GEMM2: out_acc += H @ W2[c*256:+256, :], 2 n-halves x 4 k-pieces ----
#pragma unroll
    for (int l = 0; l < 8; ++l) {
      const int h = l >> 2, q = l & 3;
      if (l < 7)      stageW2(c, (l + 1) >> 2, (l + 1) & 3, (l + 1) & 1);
      else if (c < 7) { stageX(0, 0); stageW1(c + 1, 0, 0); }
      const int wb = WOFF(l & 1);
#pragma unroll
      for (int kf = 0; kf < 2; ++kf) {
        short8 av[4], bv[4];
#pragma unroll
        for (int mf = 0; mf < 4; ++mf) {
          int m = wm * 64 + mf * 16 + lr;
          av[mf] = *(const short8*)(smem + HOFF + m * 512 +
                                    (((q * 8 + kf * 4 + lg) ^ (m & 7)) << 4));
        }
#pragma unroll
        for (int nf = 0; nf < 4; ++nf) {
          int nl = wn * 64 + nf * 16 + lr;
          bv[nf] = *(const short8*)(smem + wb + nl * 128 +
                                    (((kf * 4 + lg) ^ (nl & 7)) << 4));
        }
#pragma unroll
        for (int mf = 0; mf < 4; ++mf)
#pragma unroll
          for (int nf = 0; nf < 4; ++nf)
            acc2[mf][h * 4 + nf] = __builtin_amdgcn_mfma_f32_16x16x32_bf16(
                av[mf], bv[nf], acc2[mf][h * 4 + nf], 0, 0, 0);
      }
      __syncthreads();
    }
  }

  // ---- epilogue: out[tok] += (acc2 + b2) * w ----
  float b2v[8];
#pragma unroll
  for (int h = 0; h < 2; ++h)
#pragma unroll
    for (int nf = 0; nf < 4; ++nf)
      b2v[h * 4 + nf] = b2[e * DIM + h * 256 + wn * 64 + nf * 16 + lr];

#pragma unroll
  for (int mf = 0; mf < 4; ++mf)
#pragma unroll
    for (int r = 0; r < 4; ++r) {
      int m = wm * 64 + mf * 16 + lg * 4 + r;
      int gi = t0 + m;
      if (gi >= n_e) continue;
      int ent = lists[e * NTOK + gi];
      int t = ent & 0xFFFF;
      float w = (ent & 0x10000) ? 1.0f : 0.5f;
      float* orow = out + (size_t)t * DIM;
#pragma unroll
      for (int nc = 0; nc < 8; ++nc) {
        int col = (nc >> 2) * 256 + wn * 64 + (nc & 3) * 16 + lr;
        atomicAdd(orow + col, (acc2[mf][nc][r] + b2v[nc]) * w);
      }
    }
}

extern "C" void kernel_launch(void* const* d_in, const int* in_sizes, int n_in,
                              void* d_out, int out_size, void* d_ws, size_t ws_size,
                              hipStream_t stream) {
  const float* x      = (const float*)d_in[0];
  const int*   assign = (const int*)d_in[1];
  const float* W1     = (const float*)d_in[2];
  const float* b1     = (const float*)d_in[3];
  const float* W2     = (const float*)d_in[4];
  const float* b2     = (const float*)d_in[5];
  float* out = (float*)d_out;

  char* ws = (char*)d_ws;
  int* cnt   = (int*)ws;
  int* lists = (int*)(ws + 1024);
  ushort_t* Xb  = (ushort_t*)(ws + (2ull << 20));        // 33.6 MB
  ushort_t* W1b = (ushort_t*)(ws + 35651584ull);         // 16.8 MB
  ushort_t* W2b = (ushort_t*)(ws + 52428800ull);         // 16.8 MB, ends ~69.2 MB

  hipMemsetAsync(d_out, 0, (size_t)out_size * sizeof(float), stream);
  hipMemsetAsync(cnt, 0, 256, stream);

  moe_route<<<NTOK / 256, 256, 0, stream>>>(assign, cnt, lists);
  cvt_x<<<NTOK * DIM / 4 / 256, 256, 0, stream>>>((const float4*)x, (us4*)Xb);
  transp_cvt<<<dim3(HID / 64, DIM / 64, NE), 256, 0, stream>>>(W1, W1b, DIM, HID);
  transp_cvt<<<dim3(DIM / 64, HID / 64, NE), 256, 0, stream>>>(W2, W2b, HID, DIM);

  hipFuncSetAttribute((const void*)moe_gemm,
                      hipFuncAttributeMaxDynamicSharedMemorySize, LDS_BYTES);
  moe_gemm<<<NE * (NTOK / TM), 512, LDS_BYTES, stream>>>(Xb, W1b, b1, W2b, b2,
                                                         cnt, lists, out);
}